// Round 8
// baseline (177.437 us; speedup 1.0000x reference)
//
#include <hip/hip_runtime.h>
#include <cstddef>
#include <cstdint>

// ---------------------------------------------------------------------------
// MultiGroupDMoN forward, reduced algebraically:
//   m_g   = sum_e val
//   tr_g  = sum_e val * dot(S[src], S[dst])      (fp8 rows, 1 uint4 gather each)
//   gdS_g = sum_e val * S[dst, :]                (fp8 decode, register acc)
// R8 = R7 with the nontemporal loads fixed: __builtin_nontemporal_load needs
//     native clang vectors (ext_vector_type), not HIP_vector_type.
// ws layout (floats):
//   [OFF_E .. +3*18*EGRID)   edge partials [g][slot][block]
//   [OFF_R .. +4112)         reduced P[4096]+cs[16]   (memset 0)
//   [OFF_G .. +64)           G54 reduced accumulators
//   [OFF_F8.. +4n)           fp8 S (n rows x 16 bytes, as u32)
//   [OFF_P .. +grid1*4112)   per-block k_rows partials
// ---------------------------------------------------------------------------

#define G1_MAX   1024
#define EGRID    2048
#define NSEG     16
#define OFF_E    0
#define SZ_E     (3 * 18 * EGRID)
#define OFF_R    (OFF_E + SZ_E)
#define OFF_G    (OFF_R + 4112)
#define OFF_F8   (OFF_G + 64)

#define TROWS    32     // rows per k_rows tile
#define RPAD     280    // ushort stride per row

typedef int   iv4 __attribute__((ext_vector_type(4)));
typedef float fv4 __attribute__((ext_vector_type(4)));

#if __has_builtin(__builtin_amdgcn_cvt_pk_f32_fp8)
#define HW_FP8 1
#endif

// ---- f32 -> bf16 (RNE) ----
__device__ __forceinline__ unsigned bfr(float f)
{
    unsigned u = __float_as_uint(f);
    return (u + 0x7FFFu + ((u >> 16) & 1u)) >> 16;
}
__device__ __forceinline__ float bf_lo(unsigned u) { return __uint_as_float(u << 16); }
__device__ __forceinline__ float bf_hi(unsigned u) { return __uint_as_float(u & 0xFFFF0000u); }

// ---- software e4m3fn encode (once per S element, in k_rows) ----
__device__ __forceinline__ unsigned f32_to_e4m3(float f)
{
    unsigned bits = __float_as_uint(f);
    unsigned s = bits >> 31;
    int e32 = (int)((bits >> 23) & 255);
    unsigned m23 = bits & 0x7FFFFF;
    int e = e32 - 120;                        // e4m3 biased exponent
    unsigned out;
    if (e32 == 0) out = 0;
    else if (e <= 0) {                        // denorm: round(|f|*512)
        float av = fabsf(f);
        int q = (int)(av * 512.0f + 0.5f);
        out = (unsigned)q;
    } else if (e > 15) out = (15u << 3) | 6u;
    else {
        unsigned m3 = (m23 + 0x80000u) >> 20;
        if (m3 == 8u) { m3 = 0u; ++e; if (e > 15) { e = 15; m3 = 6u; } }
        out = ((unsigned)e << 3) | m3;
    }
    return out | (s << 7);
}

// ---- decode 16 fp8 bytes (one S row) to floats, byte order preserved ----
__device__ __forceinline__ void decode16(uint4 r, float* o, const float* lut)
{
#ifdef HW_FP8
    #pragma unroll
    for (int j = 0; j < 4; ++j) {
        unsigned u = (&r.x)[j];
        auto lo = __builtin_amdgcn_cvt_pk_f32_fp8(u, false);   // bytes 0,1
        auto hi = __builtin_amdgcn_cvt_pk_f32_fp8(u, true);    // bytes 2,3
        o[4*j]   = lo[0]; o[4*j+1] = lo[1];
        o[4*j+2] = hi[0]; o[4*j+3] = hi[1];
    }
#else
    #pragma unroll
    for (int j = 0; j < 4; ++j) {
        unsigned u = (&r.x)[j];
        #pragma unroll
        for (int q = 0; q < 4; ++q)
            o[4*j+q] = lut[(u >> (8*q)) & 255];
    }
#endif
}

__global__ void __launch_bounds__(256)
k_rows(const float* __restrict__ F, const float* __restrict__ W,
       const float* __restrict__ b, float* __restrict__ S_out,
       unsigned* __restrict__ S_f8, float* __restrict__ ws_P, int n, int n_tiles)
{
    __shared__ unsigned short Wt_bf[16][RPAD];     // Wt[k][d] bf16
    __shared__ unsigned short rows_bf[TROWS][RPAD];
    __shared__ float S_lds[TROWS][17];
    __shared__ float cs_red[256];

    const int t = threadIdx.x;

    for (int idx = t; idx < 4096; idx += 256)
        Wt_bf[idx & 15][idx >> 4] = (unsigned short)bfr(W[idx]);

    const float bk = b[t & 15];
    const int rl = t >> 4;       // logits: rows rl and rl+16
    const int kl = t & 15;       // logits: cluster
    const int kp = t & 15;       // P phase: cluster
    const int cp = t >> 4;       // P phase: 16-wide d-chunk

    float4 P0 = {0,0,0,0}, P1 = {0,0,0,0}, P2 = {0,0,0,0}, P3 = {0,0,0,0};
    float cs_acc = 0.f;
    __syncthreads();

    for (int tile = blockIdx.x; tile < n_tiles; tile += gridDim.x) {
        const int row0 = tile * TROWS;
        const float4* F4 = (const float4*)(F + (size_t)row0 * 256);
        #pragma unroll
        for (int q = 0; q < 8; ++q) {
            int idx = t + (q << 8);              // 0..2047
            int r = idx >> 6, c4 = idx & 63;
            float4 v = {0.f, 0.f, 0.f, 0.f};
            if (row0 + r < n) v = F4[idx];
            unsigned u0 = bfr(v.x) | (bfr(v.y) << 16);
            unsigned u1 = bfr(v.z) | (bfr(v.w) << 16);
            *(uint2*)&rows_bf[r][c4 << 2] = make_uint2(u0, u1);
        }
        __syncthreads();

        // ---- logits: thread (rl,kl) computes rows {rl, rl+16} . W[:,kl] ----
        float a0 = 0.f, a1 = 0.f;
        #pragma unroll 8
        for (int dd = 0; dd < 32; ++dd) {
            uint4 wv = *(const uint4*)&Wt_bf[kl][dd << 3];
            uint4 r0 = *(const uint4*)&rows_bf[rl][dd << 3];
            uint4 r1 = *(const uint4*)&rows_bf[rl + 16][dd << 3];
            #pragma unroll
            for (int j = 0; j < 4; ++j) {
                unsigned wu = (&wv.x)[j], u0 = (&r0.x)[j], u1 = (&r1.x)[j];
                float wl = bf_lo(wu), wh = bf_hi(wu);
                a0 = fmaf(bf_lo(u0), wl, a0); a0 = fmaf(bf_hi(u0), wh, a0);
                a1 = fmaf(bf_lo(u1), wl, a1); a1 = fmaf(bf_hi(u1), wh, a1);
            }
        }
        a0 += bk; a1 += bk;

        // ---- softmax over the 16 kl lanes, two rows ----
        float mx0 = a0, mx1 = a1;
        #pragma unroll
        for (int o = 8; o; o >>= 1) {
            mx0 = fmaxf(mx0, __shfl_xor(mx0, o, 16));
            mx1 = fmaxf(mx1, __shfl_xor(mx1, o, 16));
        }
        float e0 = __expf(a0 - mx0), e1 = __expf(a1 - mx1);
        float s0 = e0, s1 = e1;
        #pragma unroll
        for (int o = 8; o; o >>= 1) {
            s0 += __shfl_xor(s0, o, 16);
            s1 += __shfl_xor(s1, o, 16);
        }
        float sv0 = e0 / s0, sv1 = e1 / s1;

        const bool v0 = (row0 + rl) < n;
        const bool v1 = (row0 + rl + 16) < n;
        if (v0) { S_out[(((size_t)(row0 + rl)) << 4) + kl] = sv0; cs_acc += sv0; }
        if (v1) { S_out[(((size_t)(row0 + rl + 16)) << 4) + kl] = sv1; cs_acc += sv1; }
        S_lds[rl][kl]      = v0 ? sv0 : 0.f;
        S_lds[rl + 16][kl] = v1 ? sv1 : 0.f;
        __syncthreads();

        // fp8 pack: threads t<128: row r=t>>2, 4-elem chunk c=t&3
        if (t < 128) {
            int r = t >> 2, c = t & 3;
            int row = row0 + r;
            if (row < n) {
                unsigned u = f32_to_e4m3(S_lds[r][4*c])
                           | (f32_to_e4m3(S_lds[r][4*c+1]) << 8)
                           | (f32_to_e4m3(S_lds[r][4*c+2]) << 16)
                           | (f32_to_e4m3(S_lds[r][4*c+3]) << 24);
                S_f8[((size_t)row << 2) + c] = u;
            }
        }

        // ---- P accumulation: thread (kp,cp) owns P[kp][16cp..16cp+15] ----
        #pragma unroll 4
        for (int r = 0; r < TROWS; ++r) {
            float sv = S_lds[r][kp];
            const unsigned short* rp = &rows_bf[r][cp << 4];
            uint4 fa = *(const uint4*)&rp[0];
            uint4 fb = *(const uint4*)&rp[8];
            float f0 = bf_lo(fa.x), f1 = bf_hi(fa.x);
            float f2 = bf_lo(fa.y), f3 = bf_hi(fa.y);
            float f4 = bf_lo(fa.z), f5 = bf_hi(fa.z);
            float f6 = bf_lo(fa.w), f7 = bf_hi(fa.w);
            float f8 = bf_lo(fb.x), f9 = bf_hi(fb.x);
            float fA = bf_lo(fb.y), fB = bf_hi(fb.y);
            float fC = bf_lo(fb.z), fD = bf_hi(fb.z);
            float fE = bf_lo(fb.w), fF = bf_hi(fb.w);
            P0.x = fmaf(sv, f0, P0.x); P0.y = fmaf(sv, f1, P0.y);
            P0.z = fmaf(sv, f2, P0.z); P0.w = fmaf(sv, f3, P0.w);
            P1.x = fmaf(sv, f4, P1.x); P1.y = fmaf(sv, f5, P1.y);
            P1.z = fmaf(sv, f6, P1.z); P1.w = fmaf(sv, f7, P1.w);
            P2.x = fmaf(sv, f8, P2.x); P2.y = fmaf(sv, f9, P2.y);
            P2.z = fmaf(sv, fA, P2.z); P2.w = fmaf(sv, fB, P2.w);
            P3.x = fmaf(sv, fC, P3.x); P3.y = fmaf(sv, fD, P3.y);
            P3.z = fmaf(sv, fE, P3.z); P3.w = fmaf(sv, fF, P3.w);
        }
        __syncthreads();
    }

    {
        float* dst = ws_P + (size_t)blockIdx.x * 4112 + kp * 256 + (cp << 4);
        *(float4*)&dst[0]  = P0;
        *(float4*)&dst[4]  = P1;
        *(float4*)&dst[8]  = P2;
        *(float4*)&dst[12] = P3;
    }
    cs_red[t] = cs_acc;
    __syncthreads();
    if (t < 16) {
        float ssum = 0.f;
        #pragma unroll
        for (int i = 0; i < 16; ++i) ssum += cs_red[t + (i << 4)];
        ws_P[(size_t)blockIdx.x * 4112 + 4096 + t] = ssum;
    }
}

__global__ void __launch_bounds__(256)
k_reduce(const float* __restrict__ ws_P, float* __restrict__ ws_red, int nb)
{
    const int seg  = blockIdx.x & (NSEG - 1);
    const int jblk = blockIdx.x / NSEG;
    const int idx  = jblk * 256 + threadIdx.x;
    if (idx >= 4112) return;
    const int chunk = (nb + NSEG - 1) / NSEG;
    const int b0 = seg * chunk;
    const int b1 = min(nb, b0 + chunk);
    float s = 0.f;
    for (int bb = b0; bb < b1; ++bb)
        s += ws_P[(size_t)bb * 4112 + idx];
    atomicAdd(&ws_red[idx], s);
}

// fused edge kernel, all 3 graphs; register accumulators, no per-edge atomics.
// Edge streams loaded NON-TEMPORAL so they don't evict S8 from per-XCD L2.
__global__ void __launch_bounds__(256, 2)
k_edge(const int* __restrict__ src0, const int* __restrict__ dst0,
       const float* __restrict__ val0, int n0,
       const int* __restrict__ src1, const int* __restrict__ dst1,
       const float* __restrict__ val1, int n1,
       const int* __restrict__ src2, const int* __restrict__ dst2,
       const float* __restrict__ val2, int n2,
       const uint4* __restrict__ S8, float* __restrict__ ws_e,
       int b0, int b1)
{
#ifndef HW_FP8
    __shared__ float lut[256];
    if (threadIdx.x < 256) {
        int i = threadIdx.x;
        int e_ = (i >> 3) & 15, m_ = i & 7, s_ = i >> 7;
        float v = e_ ? ldexpf((float)(8 + m_), e_ - 10) : ldexpf((float)m_, -9);
        lut[i] = s_ ? -v : v;
    }
    __syncthreads();
    const float* lutp = lut;
#else
    const float* lutp = nullptr;
#endif

    int g, bb, nblk, nE;
    const int* src; const int* dst; const float* val;
    if ((int)blockIdx.x < b0)      { g = 0; bb = blockIdx.x;      nblk = b0;             src = src0; dst = dst0; val = val0; nE = n0; }
    else if ((int)blockIdx.x < b1) { g = 1; bb = blockIdx.x - b0; nblk = b1 - b0;        src = src1; dst = dst1; val = val1; nE = n1; }
    else                           { g = 2; bb = blockIdx.x - b1; nblk = gridDim.x - b1; src = src2; dst = dst2; val = val2; nE = n2; }

    float m_acc = 0.f, tr_acc = 0.f;
    float gds[16];
    #pragma unroll
    for (int k = 0; k < 16; ++k) gds[k] = 0.f;

    const int nv = nE >> 3;                    // 8 edges per thread-iter
    const iv4* s4 = (const iv4*)src;
    const iv4* d4 = (const iv4*)dst;
    const fv4* v4 = (const fv4*)val;
    const int stride = nblk * 256;

    for (int i = bb * 256 + threadIdx.x; i < nv; i += stride) {
        iv4 sa = __builtin_nontemporal_load(&s4[2*i]);
        iv4 sb = __builtin_nontemporal_load(&s4[2*i+1]);
        iv4 da = __builtin_nontemporal_load(&d4[2*i]);
        iv4 db = __builtin_nontemporal_load(&d4[2*i+1]);
        fv4 va = __builtin_nontemporal_load(&v4[2*i]);
        fv4 vb = __builtin_nontemporal_load(&v4[2*i+1]);
        int   is[8] = {sa[0], sa[1], sa[2], sa[3], sb[0], sb[1], sb[2], sb[3]};
        int   id[8] = {da[0], da[1], da[2], da[3], db[0], db[1], db[2], db[3]};
        float vv[8] = {va[0], va[1], va[2], va[3], vb[0], vb[1], vb[2], vb[3]};
        uint4 rs[8], rd[8];
        #pragma unroll
        for (int e = 0; e < 8; ++e) {
            rs[e] = S8[is[e]];
            rd[e] = S8[id[e]];
        }
        #pragma unroll
        for (int e = 0; e < 8; ++e) {
            float sv[16], dv[16];
            decode16(rs[e], sv, lutp);
            decode16(rd[e], dv, lutp);
            float v = vv[e];
            float dot = 0.f;
            #pragma unroll
            for (int k = 0; k < 16; ++k) dot = fmaf(sv[k], dv[k], dot);
            m_acc += v;
            tr_acc = fmaf(v, dot, tr_acc);
            #pragma unroll
            for (int k = 0; k < 16; ++k) gds[k] = fmaf(v, dv[k], gds[k]);
        }
    }

    // tail (nE % 8): handled by block 0 of this graph
    if (bb == 0) {
        int e = (nv << 3) + threadIdx.x;
        if (e < nE) {
            float sv[16], dv[16];
            decode16(S8[src[e]], sv, lutp);
            decode16(S8[dst[e]], dv, lutp);
            float v = val[e];
            float dot = 0.f;
            #pragma unroll
            for (int k = 0; k < 16; ++k) dot = fmaf(sv[k], dv[k], dot);
            m_acc += v;
            tr_acc = fmaf(v, dot, tr_acc);
            #pragma unroll
            for (int k = 0; k < 16; ++k) gds[k] = fmaf(v, dv[k], gds[k]);
        }
    }

    #pragma unroll
    for (int o = 32; o; o >>= 1) {
        m_acc  += __shfl_xor(m_acc, o);
        tr_acc += __shfl_xor(tr_acc, o);
        #pragma unroll
        for (int k = 0; k < 16; ++k) gds[k] += __shfl_xor(gds[k], o);
    }
    __shared__ float wred[4][18];
    const int wid = threadIdx.x >> 6, lane = threadIdx.x & 63;
    if (lane == 0) {
        wred[wid][0] = m_acc; wred[wid][1] = tr_acc;
        #pragma unroll
        for (int k = 0; k < 16; ++k) wred[wid][2 + k] = gds[k];
    }
    __syncthreads();
    if (threadIdx.x < 18) {
        float s = wred[0][threadIdx.x] + wred[1][threadIdx.x]
                + wred[2][threadIdx.x] + wred[3][threadIdx.x];
        ws_e[(size_t)g * 18 * EGRID + (size_t)threadIdx.x * EGRID + bb] = s;
    }
}

// one block per (g,slot): coalesced reduce of per-graph partials -> G54
__global__ void __launch_bounds__(256)
k_ereduce(const float* __restrict__ ws_e, float* __restrict__ G54,
          int g0, int g1, int g2)
{
    const int p = blockIdx.x;            // 0..53
    const int g = p / 18, slot = p % 18;
    int grids[3] = {g0, g1, g2};
    const int gb = grids[g];
    const float* base = ws_e + (size_t)g * 18 * EGRID + (size_t)slot * EGRID;

    const int t = threadIdx.x;
    float s = 0.f;
    for (int bb = t; bb < gb; bb += 256) s += base[bb];
    #pragma unroll
    for (int o = 32; o; o >>= 1) s += __shfl_xor(s, o);

    __shared__ float wr[4];
    if ((t & 63) == 0) wr[t >> 6] = s;
    __syncthreads();
    if (t == 0) G54[p] = wr[0] + wr[1] + wr[2] + wr[3];
}

__global__ void __launch_bounds__(256)
k_final(const float* __restrict__ ws_red, const float* __restrict__ G54,
        const void* __restrict__ lamda_ptr, float* __restrict__ out, int n)
{
    __shared__ float G[54];
    const int t = threadIdx.x;
    if (t < 54) G[t] = G54[t];
    __syncthreads();

    const float* P  = ws_red;
    const float* cs = ws_red + 4096;

    const float scale = 1.0507009873554805f;
    const float alpha = 1.6732632423543772f;
    for (int idx = t; idx < 4096; idx += 256) {
        int k = idx >> 8;
        float x = P[idx] / cs[k];
        float y = x > 0.f ? scale * x : scale * alpha * (expf(x) - 1.f);
        out[idx] = y;
    }

    if (t == 0) {
        int   li = *(const int*)lamda_ptr;
        float lf = *(const float*)lamda_ptr;
        float lamda = (li > -100000 && li < 100000) ? (float)li : lf;

        float m = G[0], trA = G[1];
        float ds2 = 0.f;
        for (int k = 0; k < 16; ++k) ds2 += G[2 + k] * G[2 + k];
        float spectral = -(trA - ds2 / (2.f * m)) / (2.f * m);

        float Q[2], gm[2];
        for (int g = 0; g < 2; ++g) {
            const float* Gg = G + 18 * (g + 1);
            float mg = Gg[0], trg = Gg[1];
            float gds2 = 0.f;
            for (int k = 0; k < 16; ++k) gds2 += Gg[2 + k] * Gg[2 + k];
            float safe = mg > 0.f ? mg : 1.f;
            float q = (trg - gds2 / (2.f * safe)) / (2.f * m);
            Q[g]  = mg > 0.f ? q : 0.f;
            gm[g] = mg;
        }
        float Qmin = fminf(Q[0], Q[1]);
        float gmean = 0.5f * (gm[0] + gm[1]);
        float fairness = (m / (gmean + 1e-8f)) * (-Qmin);

        float csn = 0.f;
        for (int k = 0; k < 16; ++k) csn += cs[k] * cs[k];
        float collapse = (sqrtf(csn) / (float)n) * 4.f - 1.f;

        out[4096 + (size_t)n * 16] = spectral + lamda * fairness + 0.1f * collapse;
    }
}

extern "C" void kernel_launch(void* const* d_in, const int* in_sizes, int n_in,
                              void* d_out, int out_size, void* d_ws, size_t ws_size,
                              hipStream_t stream)
{
    const float* F       = (const float*)d_in[0];
    const float* W       = (const float*)d_in[1];
    const float* b       = (const float*)d_in[2];
    const int*   adj_src = (const int*)d_in[3];
    const int*   adj_dst = (const int*)d_in[4];
    const float* adj_val = (const float*)d_in[5];
    const int*   g1_src  = (const int*)d_in[6];
    const int*   g1_dst  = (const int*)d_in[7];
    const float* g1_val  = (const float*)d_in[8];
    const int*   g2_src  = (const int*)d_in[9];
    const int*   g2_dst  = (const int*)d_in[10];
    const float* g2_val  = (const float*)d_in[11];
    const void*  lamda_p = d_in[12];

    const int n  = in_sizes[0] / 256;
    const int nE = in_sizes[3];
    const int n1 = in_sizes[6];
    const int n2 = in_sizes[9];

    float* out   = (float*)d_out;
    float* S_out = out + 4096;

    float* ws   = (float*)d_ws;
    float* ws_e = ws + OFF_E;
    float* ws_r = ws + OFF_R;
    float* ws_g = ws + OFF_G;
    unsigned* S8 = (unsigned*)(ws + OFF_F8);
    const size_t off_p = (size_t)OFF_F8 + (size_t)n * 4;
    float* ws_P = ws + off_p;

    const int n_tiles = (n + TROWS - 1) / TROWS;
    long avail = ((long)(ws_size / 4) - (long)off_p) / 4112;
    int grid1 = n_tiles < G1_MAX ? n_tiles : G1_MAX;
    if (avail < grid1) grid1 = (int)avail;
    if (grid1 < 1) grid1 = 1;

    (void)hipMemsetAsync(ws_r, 0, 4112 * sizeof(float), stream);

    k_rows<<<grid1, 256, 0, stream>>>(F, W, b, S_out, S8, ws_P, n, n_tiles);
    k_reduce<<<17 * NSEG, 256, 0, stream>>>(ws_P, ws_r, grid1);

    auto eg = [](int ne) { int g = (ne / 8 + 255) / 256; if (g < 1) g = 1;
                           return g < EGRID ? g : EGRID; };
    const int b0 = eg(nE), b1g = eg(n1), b2g = eg(n2);
    k_edge<<<b0 + b1g + b2g, 256, 0, stream>>>(
        adj_src, adj_dst, adj_val, nE,
        g1_src, g1_dst, g1_val, n1,
        g2_src, g2_dst, g2_val, n2,
        (const uint4*)S8, ws_e, b0, b0 + b1g);

    k_ereduce<<<54, 256, 0, stream>>>(ws_e, ws_g, b0, b1g, b2g);
    k_final<<<1, 256, 0, stream>>>(ws_r, ws_g, lamda_p, out, n);
}

// Round 10
// 162.251 us; speedup vs baseline: 1.0936x; 1.0936x over previous
//
#include <hip/hip_runtime.h>
#include <cstddef>
#include <cstdint>

// ---------------------------------------------------------------------------
// MultiGroupDMoN forward, reduced algebraically:
//   m_g   = sum_e val
//   tr_g  = sum_e val * dot(S[src], S[dst])      (fp8 rows, 1 uint4 gather each)
//   gdS_g = sum_e val * S[dst, :]                (fp8 decode, register acc)
// R10 = R9 with pk16 fixed: cvt_pkrtz returns __fp16x2, bit_cast to _Float16x2.
// ws layout (floats):
//   [OFF_E .. +3*18*EGRID)   edge partials [g][slot][block]
//   [OFF_R .. +4112)         reduced P[4096]+cs[16]   (memset 0)
//   [OFF_G .. +64)           G54 reduced accumulators
//   [OFF_F8.. +4n)           fp8 S (n rows x 16 bytes, as u32)
//   [OFF_P .. +grid1*4112)   per-block k_rows partials
// ---------------------------------------------------------------------------

#define G1_MAX   1024
#define EGRID    2048
#define NSEG     16
#define OFF_E    0
#define SZ_E     (3 * 18 * EGRID)
#define OFF_R    (OFF_E + SZ_E)
#define OFF_G    (OFF_R + 4112)
#define OFF_F8   (OFF_G + 64)

#define TROWS    32     // rows per k_rows tile
#define RPAD2    134    // h2 (4B) units per row: 134 dw == 6 mod 32 banks

#define BLK0     384    // k_edge blocks: adj
#define BLK12    192    // k_edge blocks: g1, g2

typedef int      iv4 __attribute__((ext_vector_type(4)));
typedef float    fv4 __attribute__((ext_vector_type(4)));
typedef _Float16 hh;
typedef hh       h2  __attribute__((ext_vector_type(2)));

#if __has_builtin(__builtin_amdgcn_cvt_pk_f32_fp8)
#define HW_FP8 1
#endif

__device__ __forceinline__ h2 bch2(unsigned u) { return __builtin_bit_cast(h2, u); }

__device__ __forceinline__ float fdot2(h2 a, h2 b, float c)
{
#if __has_builtin(__builtin_amdgcn_fdot2)
    return __builtin_amdgcn_fdot2(a, b, c, false);
#else
    return fmaf((float)a[0], (float)b[0], fmaf((float)a[1], (float)b[1], c));
#endif
}

__device__ __forceinline__ h2 pk16(float x, float y)
{
#if __has_builtin(__builtin_amdgcn_cvt_pkrtz)
    return __builtin_bit_cast(h2, __builtin_amdgcn_cvt_pkrtz(x, y));
#else
    h2 r; r[0] = (hh)x; r[1] = (hh)y; return r;
#endif
}

// ---- software e4m3fn encode (once per S element, in k_rows) ----
__device__ __forceinline__ unsigned f32_to_e4m3(float f)
{
    unsigned bits = __float_as_uint(f);
    unsigned s = bits >> 31;
    int e32 = (int)((bits >> 23) & 255);
    unsigned m23 = bits & 0x7FFFFF;
    int e = e32 - 120;                        // e4m3 biased exponent
    unsigned out;
    if (e32 == 0) out = 0;
    else if (e <= 0) {                        // denorm: round(|f|*512)
        float av = fabsf(f);
        int q = (int)(av * 512.0f + 0.5f);
        out = (unsigned)q;
    } else if (e > 15) out = (15u << 3) | 6u;
    else {
        unsigned m3 = (m23 + 0x80000u) >> 20;
        if (m3 == 8u) { m3 = 0u; ++e; if (e > 15) { e = 15; m3 = 6u; } }
        out = ((unsigned)e << 3) | m3;
    }
    return out | (s << 7);
}

// ---- decode 16 fp8 bytes (one S row) to floats, byte order preserved ----
__device__ __forceinline__ void decode16(uint4 r, float* o, const float* lut)
{
#ifdef HW_FP8
    #pragma unroll
    for (int j = 0; j < 4; ++j) {
        unsigned u = (&r.x)[j];
        auto lo = __builtin_amdgcn_cvt_pk_f32_fp8(u, false);   // bytes 0,1
        auto hi = __builtin_amdgcn_cvt_pk_f32_fp8(u, true);    // bytes 2,3
        o[4*j]   = lo[0]; o[4*j+1] = lo[1];
        o[4*j+2] = hi[0]; o[4*j+3] = hi[1];
    }
#else
    #pragma unroll
    for (int j = 0; j < 4; ++j) {
        unsigned u = (&r.x)[j];
        #pragma unroll
        for (int q = 0; q < 4; ++q)
            o[4*j+q] = lut[(u >> (8*q)) & 255];
    }
#endif
}

__global__ void __launch_bounds__(256)
k_rows(const float* __restrict__ F, const float* __restrict__ W,
       const float* __restrict__ b, float* __restrict__ S_out,
       unsigned* __restrict__ S_f8, float* __restrict__ ws_P, int n, int n_tiles)
{
    __shared__ h2    Wt_h2[16][RPAD2];      // Wt[k][d-pair], fp16x2
    __shared__ h2    rows_h2[TROWS][RPAD2];
    __shared__ float S_lds[TROWS][17];
    __shared__ float cs_red[256];

    const int t = threadIdx.x;

    // stage Wt: Wt_h2[k][p] = {W[2p][k], W[2p+1][k]}
    for (int idx = t; idx < 2048; idx += 256) {
        int k = idx & 15, p = idx >> 4;
        Wt_h2[k][p] = pk16(W[(2*p) * 16 + k], W[(2*p + 1) * 16 + k]);
    }

    const float bk = b[t & 15];
    const int rl = t >> 4;       // logits: rows rl and rl+16
    const int kl = t & 15;       // logits: cluster
    const int kp = t & 15;       // P phase: cluster
    const int cp = t >> 4;       // P phase: 16-wide d-chunk

    h2 Pa[8];
    #pragma unroll
    for (int j = 0; j < 8; ++j) Pa[j] = pk16(0.f, 0.f);
    float cs_acc = 0.f;
    __syncthreads();

    for (int tile = blockIdx.x; tile < n_tiles; tile += gridDim.x) {
        const int row0 = tile * TROWS;
        const float4* F4 = (const float4*)(F + (size_t)row0 * 256);
        // stage 32 rows as fp16: 2048 float4 -> 8 per thread
        #pragma unroll
        for (int q = 0; q < 8; ++q) {
            int idx = t + (q << 8);              // 0..2047
            int r = idx >> 6, c4 = idx & 63;
            float4 v = {0.f, 0.f, 0.f, 0.f};
            if (row0 + r < n) v = F4[idx];
            rows_h2[r][c4 * 2]     = pk16(v.x, v.y);
            rows_h2[r][c4 * 2 + 1] = pk16(v.z, v.w);
        }
        __syncthreads();

        // ---- logits: thread (rl,kl): rows {rl, rl+16} . W[:,kl] via dot2 ----
        float a0 = 0.f, a1 = 0.f;
        #pragma unroll 8
        for (int dd = 0; dd < 32; ++dd) {          // 8 dims per iter
            uint4 wv = *(const uint4*)&Wt_h2[kl][dd << 2];
            uint4 r0 = *(const uint4*)&rows_h2[rl][dd << 2];
            uint4 r1 = *(const uint4*)&rows_h2[rl + 16][dd << 2];
            #pragma unroll
            for (int j = 0; j < 4; ++j) {
                h2 wj = bch2((&wv.x)[j]);
                a0 = fdot2(wj, bch2((&r0.x)[j]), a0);
                a1 = fdot2(wj, bch2((&r1.x)[j]), a1);
            }
        }
        a0 += bk; a1 += bk;

        // ---- softmax over the 16 kl lanes, two rows ----
        float mx0 = a0, mx1 = a1;
        #pragma unroll
        for (int o = 8; o; o >>= 1) {
            mx0 = fmaxf(mx0, __shfl_xor(mx0, o, 16));
            mx1 = fmaxf(mx1, __shfl_xor(mx1, o, 16));
        }
        float e0 = __expf(a0 - mx0), e1 = __expf(a1 - mx1);
        float s0 = e0, s1 = e1;
        #pragma unroll
        for (int o = 8; o; o >>= 1) {
            s0 += __shfl_xor(s0, o, 16);
            s1 += __shfl_xor(s1, o, 16);
        }
        float sv0 = e0 / s0, sv1 = e1 / s1;

        const bool v0 = (row0 + rl) < n;
        const bool v1 = (row0 + rl + 16) < n;
        if (v0) { S_out[(((size_t)(row0 + rl)) << 4) + kl] = sv0; cs_acc += sv0; }
        if (v1) { S_out[(((size_t)(row0 + rl + 16)) << 4) + kl] = sv1; cs_acc += sv1; }
        S_lds[rl][kl]      = v0 ? sv0 : 0.f;
        S_lds[rl + 16][kl] = v1 ? sv1 : 0.f;
        __syncthreads();

        // fp8 pack: threads t<128: row r=t>>2, 4-elem chunk c=t&3
        if (t < 128) {
            int r = t >> 2, c = t & 3;
            int row = row0 + r;
            if (row < n) {
                unsigned u = f32_to_e4m3(S_lds[r][4*c])
                           | (f32_to_e4m3(S_lds[r][4*c+1]) << 8)
                           | (f32_to_e4m3(S_lds[r][4*c+2]) << 16)
                           | (f32_to_e4m3(S_lds[r][4*c+3]) << 24);
                S_f8[((size_t)row << 2) + c] = u;
            }
        }

        // ---- P accumulation: thread (kp,cp) owns P[kp][16cp..16cp+15] ----
        #pragma unroll 4
        for (int r = 0; r < TROWS; ++r) {
            float sv = S_lds[r][kp];
            h2 svh = pk16(sv, sv);
            uint4 fa = *(const uint4*)&rows_h2[r][cp << 3];
            uint4 fb = *(const uint4*)&rows_h2[r][(cp << 3) + 4];
            #pragma unroll
            for (int j = 0; j < 4; ++j) {
                Pa[j]     = svh * bch2((&fa.x)[j]) + Pa[j];      // v_pk_fma_f16
                Pa[4 + j] = svh * bch2((&fb.x)[j]) + Pa[4 + j];
            }
        }
        __syncthreads();
    }

    // ---- flush partials (f32) to private per-block slot ----
    {
        float o16[16];
        #pragma unroll
        for (int j = 0; j < 8; ++j) {
            o16[2*j]     = (float)Pa[j][0];
            o16[2*j + 1] = (float)Pa[j][1];
        }
        float* dst = ws_P + (size_t)blockIdx.x * 4112 + kp * 256 + (cp << 4);
        #pragma unroll
        for (int j = 0; j < 4; ++j)
            *(float4*)&dst[4*j] = make_float4(o16[4*j], o16[4*j+1], o16[4*j+2], o16[4*j+3]);
    }
    cs_red[t] = cs_acc;
    __syncthreads();
    if (t < 16) {
        float ssum = 0.f;
        #pragma unroll
        for (int i = 0; i < 16; ++i) ssum += cs_red[t + (i << 4)];
        ws_P[(size_t)blockIdx.x * 4112 + 4096 + t] = ssum;
    }
}

__global__ void __launch_bounds__(256)
k_reduce(const float* __restrict__ ws_P, float* __restrict__ ws_red, int nb)
{
    const int seg  = blockIdx.x & (NSEG - 1);
    const int jblk = blockIdx.x / NSEG;
    const int idx  = jblk * 256 + threadIdx.x;
    if (idx >= 4112) return;
    const int chunk = (nb + NSEG - 1) / NSEG;
    const int b0 = seg * chunk;
    const int b1 = min(nb, b0 + chunk);
    float s = 0.f;
    for (int bb = b0; bb < b1; ++bb)
        s += ws_P[(size_t)bb * 4112 + idx];
    atomicAdd(&ws_red[idx], s);
}

// fused edge kernel, all 3 graphs; register accumulators, no per-edge atomics.
// Small fixed grid -> several iterations per thread (pipelining + amortized tail).
__global__ void __launch_bounds__(256, 2)
k_edge(const int* __restrict__ src0, const int* __restrict__ dst0,
       const float* __restrict__ val0, int n0,
       const int* __restrict__ src1, const int* __restrict__ dst1,
       const float* __restrict__ val1, int n1,
       const int* __restrict__ src2, const int* __restrict__ dst2,
       const float* __restrict__ val2, int n2,
       const uint4* __restrict__ S8, float* __restrict__ ws_e,
       int b0, int b1)
{
#ifndef HW_FP8
    __shared__ float lut[256];
    if (threadIdx.x < 256) {
        int i = threadIdx.x;
        int e_ = (i >> 3) & 15, m_ = i & 7, s_ = i >> 7;
        float v = e_ ? ldexpf((float)(8 + m_), e_ - 10) : ldexpf((float)m_, -9);
        lut[i] = s_ ? -v : v;
    }
    __syncthreads();
    const float* lutp = lut;
#else
    const float* lutp = nullptr;
#endif

    int g, bb, nblk, nE;
    const int* src; const int* dst; const float* val;
    if ((int)blockIdx.x < b0)      { g = 0; bb = blockIdx.x;      nblk = b0;             src = src0; dst = dst0; val = val0; nE = n0; }
    else if ((int)blockIdx.x < b1) { g = 1; bb = blockIdx.x - b0; nblk = b1 - b0;        src = src1; dst = dst1; val = val1; nE = n1; }
    else                           { g = 2; bb = blockIdx.x - b1; nblk = gridDim.x - b1; src = src2; dst = dst2; val = val2; nE = n2; }

    float m_acc = 0.f, tr_acc = 0.f;
    float gds[16];
    #pragma unroll
    for (int k = 0; k < 16; ++k) gds[k] = 0.f;

    const int nv = nE >> 3;                    // 8 edges per thread-iter
    const iv4* s4 = (const iv4*)src;
    const iv4* d4 = (const iv4*)dst;
    const fv4* v4 = (const fv4*)val;
    const int stride = nblk * 256;

    for (int i = bb * 256 + threadIdx.x; i < nv; i += stride) {
        iv4 sa = __builtin_nontemporal_load(&s4[2*i]);
        iv4 sb = __builtin_nontemporal_load(&s4[2*i+1]);
        iv4 da = __builtin_nontemporal_load(&d4[2*i]);
        iv4 db = __builtin_nontemporal_load(&d4[2*i+1]);
        fv4 va = __builtin_nontemporal_load(&v4[2*i]);
        fv4 vb = __builtin_nontemporal_load(&v4[2*i+1]);
        int   is[8] = {sa[0], sa[1], sa[2], sa[3], sb[0], sb[1], sb[2], sb[3]};
        int   id[8] = {da[0], da[1], da[2], da[3], db[0], db[1], db[2], db[3]};
        float vv[8] = {va[0], va[1], va[2], va[3], vb[0], vb[1], vb[2], vb[3]};
        uint4 rs[8], rd[8];
        #pragma unroll
        for (int e = 0; e < 8; ++e) {
            rs[e] = S8[is[e]];
            rd[e] = S8[id[e]];
        }
        #pragma unroll
        for (int e = 0; e < 8; ++e) {
            float sv[16], dv[16];
            decode16(rs[e], sv, lutp);
            decode16(rd[e], dv, lutp);
            float v = vv[e];
            float dot = 0.f;
            #pragma unroll
            for (int k = 0; k < 16; ++k) dot = fmaf(sv[k], dv[k], dot);
            m_acc += v;
            tr_acc = fmaf(v, dot, tr_acc);
            #pragma unroll
            for (int k = 0; k < 16; ++k) gds[k] = fmaf(v, dv[k], gds[k]);
        }
    }

    // tail (nE % 8): handled by block 0 of this graph
    if (bb == 0) {
        int e = (nv << 3) + threadIdx.x;
        if (e < nE) {
            float sv[16], dv[16];
            decode16(S8[src[e]], sv, lutp);
            decode16(S8[dst[e]], dv, lutp);
            float v = val[e];
            float dot = 0.f;
            #pragma unroll
            for (int k = 0; k < 16; ++k) dot = fmaf(sv[k], dv[k], dot);
            m_acc += v;
            tr_acc = fmaf(v, dot, tr_acc);
            #pragma unroll
            for (int k = 0; k < 16; ++k) gds[k] = fmaf(v, dv[k], gds[k]);
        }
    }

    #pragma unroll
    for (int o = 32; o; o >>= 1) {
        m_acc  += __shfl_xor(m_acc, o);
        tr_acc += __shfl_xor(tr_acc, o);
        #pragma unroll
        for (int k = 0; k < 16; ++k) gds[k] += __shfl_xor(gds[k], o);
    }
    __shared__ float wred[4][18];
    const int wid = threadIdx.x >> 6, lane = threadIdx.x & 63;
    if (lane == 0) {
        wred[wid][0] = m_acc; wred[wid][1] = tr_acc;
        #pragma unroll
        for (int k = 0; k < 16; ++k) wred[wid][2 + k] = gds[k];
    }
    __syncthreads();
    if (threadIdx.x < 18) {
        float s = wred[0][threadIdx.x] + wred[1][threadIdx.x]
                + wred[2][threadIdx.x] + wred[3][threadIdx.x];
        ws_e[(size_t)g * 18 * EGRID + (size_t)threadIdx.x * EGRID + bb] = s;
    }
}

// one block per (g,slot): coalesced reduce of per-graph partials -> G54
__global__ void __launch_bounds__(256)
k_ereduce(const float* __restrict__ ws_e, float* __restrict__ G54,
          int g0, int g1, int g2)
{
    const int p = blockIdx.x;            // 0..53
    const int g = p / 18, slot = p % 18;
    int grids[3] = {g0, g1, g2};
    const int gb = grids[g];
    const float* base = ws_e + (size_t)g * 18 * EGRID + (size_t)slot * EGRID;

    const int t = threadIdx.x;
    float s = 0.f;
    for (int bb = t; bb < gb; bb += 256) s += base[bb];
    #pragma unroll
    for (int o = 32; o; o >>= 1) s += __shfl_xor(s, o);

    __shared__ float wr[4];
    if ((t & 63) == 0) wr[t >> 6] = s;
    __syncthreads();
    if (t == 0) G54[p] = wr[0] + wr[1] + wr[2] + wr[3];
}

__global__ void __launch_bounds__(256)
k_final(const float* __restrict__ ws_red, const float* __restrict__ G54,
        const void* __restrict__ lamda_ptr, float* __restrict__ out, int n)
{
    __shared__ float G[54];
    const int t = threadIdx.x;
    if (t < 54) G[t] = G54[t];
    __syncthreads();

    const float* P  = ws_red;
    const float* cs = ws_red + 4096;

    const float scale = 1.0507009873554805f;
    const float alpha = 1.6732632423543772f;
    for (int idx = t; idx < 4096; idx += 256) {
        int k = idx >> 8;
        float x = P[idx] / cs[k];
        float y = x > 0.f ? scale * x : scale * alpha * (expf(x) - 1.f);
        out[idx] = y;
    }

    if (t == 0) {
        int   li = *(const int*)lamda_ptr;
        float lf = *(const float*)lamda_ptr;
        float lamda = (li > -100000 && li < 100000) ? (float)li : lf;

        float m = G[0], trA = G[1];
        float ds2 = 0.f;
        for (int k = 0; k < 16; ++k) ds2 += G[2 + k] * G[2 + k];
        float spectral = -(trA - ds2 / (2.f * m)) / (2.f * m);

        float Q[2], gm[2];
        for (int g = 0; g < 2; ++g) {
            const float* Gg = G + 18 * (g + 1);
            float mg = Gg[0], trg = Gg[1];
            float gds2 = 0.f;
            for (int k = 0; k < 16; ++k) gds2 += Gg[2 + k] * Gg[2 + k];
            float safe = mg > 0.f ? mg : 1.f;
            float q = (trg - gds2 / (2.f * safe)) / (2.f * m);
            Q[g]  = mg > 0.f ? q : 0.f;
            gm[g] = mg;
        }
        float Qmin = fminf(Q[0], Q[1]);
        float gmean = 0.5f * (gm[0] + gm[1]);
        float fairness = (m / (gmean + 1e-8f)) * (-Qmin);

        float csn = 0.f;
        for (int k = 0; k < 16; ++k) csn += cs[k] * cs[k];
        float collapse = (sqrtf(csn) / (float)n) * 4.f - 1.f;

        out[4096 + (size_t)n * 16] = spectral + lamda * fairness + 0.1f * collapse;
    }
}

extern "C" void kernel_launch(void* const* d_in, const int* in_sizes, int n_in,
                              void* d_out, int out_size, void* d_ws, size_t ws_size,
                              hipStream_t stream)
{
    const float* F       = (const float*)d_in[0];
    const float* W       = (const float*)d_in[1];
    const float* b       = (const float*)d_in[2];
    const int*   adj_src = (const int*)d_in[3];
    const int*   adj_dst = (const int*)d_in[4];
    const float* adj_val = (const float*)d_in[5];
    const int*   g1_src  = (const int*)d_in[6];
    const int*   g1_dst  = (const int*)d_in[7];
    const float* g1_val  = (const float*)d_in[8];
    const int*   g2_src  = (const int*)d_in[9];
    const int*   g2_dst  = (const int*)d_in[10];
    const float* g2_val  = (const float*)d_in[11];
    const void*  lamda_p = d_in[12];

    const int n  = in_sizes[0] / 256;
    const int nE = in_sizes[3];
    const int n1 = in_sizes[6];
    const int n2 = in_sizes[9];

    float* out   = (float*)d_out;
    float* S_out = out + 4096;

    float* ws   = (float*)d_ws;
    float* ws_e = ws + OFF_E;
    float* ws_r = ws + OFF_R;
    float* ws_g = ws + OFF_G;
    unsigned* S8 = (unsigned*)(ws + OFF_F8);
    const size_t off_p = (size_t)OFF_F8 + (size_t)n * 4;
    float* ws_P = ws + off_p;

    const int n_tiles = (n + TROWS - 1) / TROWS;
    long avail = ((long)(ws_size / 4) - (long)off_p) / 4112;
    int grid1 = n_tiles < G1_MAX ? n_tiles : G1_MAX;
    if (avail < grid1) grid1 = (int)avail;
    if (grid1 < 1) grid1 = 1;

    (void)hipMemsetAsync(ws_r, 0, 4112 * sizeof(float), stream);

    k_rows<<<grid1, 256, 0, stream>>>(F, W, b, S_out, S8, ws_P, n, n_tiles);
    k_reduce<<<17 * NSEG, 256, 0, stream>>>(ws_P, ws_r, grid1);

    const int b0 = BLK0, b1g = BLK12, b2g = BLK12;
    k_edge<<<b0 + b1g + b2g, 256, 0, stream>>>(
        adj_src, adj_dst, adj_val, nE,
        g1_src, g1_dst, g1_val, n1,
        g2_src, g2_dst, g2_val, n2,
        (const uint4*)S8, ws_e, b0, b0 + b1g);

    k_ereduce<<<54, 256, 0, stream>>>(ws_e, ws_g, b0, b1g, b2g);
    k_final<<<1, 256, 0, stream>>>(ws_r, ws_g, lamda_p, out, n);
}

// Round 11
// 153.213 us; speedup vs baseline: 1.1581x; 1.0590x over previous
//
#include <hip/hip_runtime.h>
#include <cstddef>
#include <cstdint>

// ---------------------------------------------------------------------------
// MultiGroupDMoN forward, reduced algebraically:
//   m_g   = sum_e val
//   tr_g  = sum_e val * dot(S[src], S[dst])      (fp8 rows, 1 uint4 gather each)
//   gdS_g = sum_e val * S[dst, :]                (fp8 decode, register acc)
// R11: k_edge concurrency fix: 4 edges/iter (8 gathers, ~65 VGPR) x 2048
//      blocks -> ~24+ waves/CU resident (was 5; gathers were MSHR-starved at
//      0.25/cy/CU). k_rows: register prefetch of next tile's F while
//      computing current (hides HBM latency under logits/P).
// ws layout (floats):
//   [OFF_E .. +3*18*EGRID)   edge partials [g][slot][block]
//   [OFF_R .. +4112)         reduced P[4096]+cs[16]   (memset 0)
//   [OFF_G .. +64)           G54 reduced accumulators
//   [OFF_F8.. +4n)           fp8 S (n rows x 16 bytes, as u32)
//   [OFF_P .. +grid1*4112)   per-block k_rows partials
// ---------------------------------------------------------------------------

#define G1_MAX   1024
#define EGRID    2048
#define NSEG     16
#define OFF_E    0
#define SZ_E     (3 * 18 * EGRID)
#define OFF_R    (OFF_E + SZ_E)
#define OFF_G    (OFF_R + 4112)
#define OFF_F8   (OFF_G + 64)

#define TROWS    32     // rows per k_rows tile
#define RPAD2    134    // h2 (4B) units per row: 134 dw == 6 mod 32 banks

#define BLK0     1024   // k_edge blocks: adj
#define BLK12    512    // k_edge blocks: g1, g2

typedef int      iv4 __attribute__((ext_vector_type(4)));
typedef float    fv4 __attribute__((ext_vector_type(4)));
typedef _Float16 hh;
typedef hh       h2  __attribute__((ext_vector_type(2)));

#if __has_builtin(__builtin_amdgcn_cvt_pk_f32_fp8)
#define HW_FP8 1
#endif

__device__ __forceinline__ h2 bch2(unsigned u) { return __builtin_bit_cast(h2, u); }

__device__ __forceinline__ float fdot2(h2 a, h2 b, float c)
{
#if __has_builtin(__builtin_amdgcn_fdot2)
    return __builtin_amdgcn_fdot2(a, b, c, false);
#else
    return fmaf((float)a[0], (float)b[0], fmaf((float)a[1], (float)b[1], c));
#endif
}

__device__ __forceinline__ h2 pk16(float x, float y)
{
#if __has_builtin(__builtin_amdgcn_cvt_pkrtz)
    return __builtin_bit_cast(h2, __builtin_amdgcn_cvt_pkrtz(x, y));
#else
    h2 r; r[0] = (hh)x; r[1] = (hh)y; return r;
#endif
}

// ---- software e4m3fn encode (once per S element, in k_rows) ----
__device__ __forceinline__ unsigned f32_to_e4m3(float f)
{
    unsigned bits = __float_as_uint(f);
    unsigned s = bits >> 31;
    int e32 = (int)((bits >> 23) & 255);
    unsigned m23 = bits & 0x7FFFFF;
    int e = e32 - 120;                        // e4m3 biased exponent
    unsigned out;
    if (e32 == 0) out = 0;
    else if (e <= 0) {                        // denorm: round(|f|*512)
        float av = fabsf(f);
        int q = (int)(av * 512.0f + 0.5f);
        out = (unsigned)q;
    } else if (e > 15) out = (15u << 3) | 6u;
    else {
        unsigned m3 = (m23 + 0x80000u) >> 20;
        if (m3 == 8u) { m3 = 0u; ++e; if (e > 15) { e = 15; m3 = 6u; } }
        out = ((unsigned)e << 3) | m3;
    }
    return out | (s << 7);
}

// ---- decode 16 fp8 bytes (one S row) to floats, byte order preserved ----
__device__ __forceinline__ void decode16(uint4 r, float* o, const float* lut)
{
#ifdef HW_FP8
    #pragma unroll
    for (int j = 0; j < 4; ++j) {
        unsigned u = (&r.x)[j];
        auto lo = __builtin_amdgcn_cvt_pk_f32_fp8(u, false);   // bytes 0,1
        auto hi = __builtin_amdgcn_cvt_pk_f32_fp8(u, true);    // bytes 2,3
        o[4*j]   = lo[0]; o[4*j+1] = lo[1];
        o[4*j+2] = hi[0]; o[4*j+3] = hi[1];
    }
#else
    #pragma unroll
    for (int j = 0; j < 4; ++j) {
        unsigned u = (&r.x)[j];
        #pragma unroll
        for (int q = 0; q < 4; ++q)
            o[4*j+q] = lut[(u >> (8*q)) & 255];
    }
#endif
}

__global__ void __launch_bounds__(256)
k_rows(const float* __restrict__ F, const float* __restrict__ W,
       const float* __restrict__ b, float* __restrict__ S_out,
       unsigned* __restrict__ S_f8, float* __restrict__ ws_P, int n, int n_tiles)
{
    __shared__ h2    Wt_h2[16][RPAD2];      // Wt[k][d-pair], fp16x2
    __shared__ h2    rows_h2[TROWS][RPAD2];
    __shared__ float S_lds[TROWS][17];
    __shared__ float cs_red[256];

    const int t = threadIdx.x;

    // stage Wt: Wt_h2[k][p] = {W[2p][k], W[2p+1][k]}
    for (int idx = t; idx < 2048; idx += 256) {
        int k = idx & 15, p = idx >> 4;
        Wt_h2[k][p] = pk16(W[(2*p) * 16 + k], W[(2*p + 1) * 16 + k]);
    }

    const float bk = b[t & 15];
    const int rl = t >> 4;       // logits: rows rl and rl+16
    const int kl = t & 15;       // logits: cluster
    const int kp = t & 15;       // P phase: cluster
    const int cp = t >> 4;       // P phase: 16-wide d-chunk

    h2 Pa[8];
    #pragma unroll
    for (int j = 0; j < 8; ++j) Pa[j] = pk16(0.f, 0.f);
    float cs_acc = 0.f;

    // register prefetch buffer: 8 float4 = this thread's slice of a tile
    float4 stg[8];
    auto load_tile = [&](int tl) {
        const float4* F4 = (const float4*)(F + (size_t)tl * TROWS * 256);
        #pragma unroll
        for (int q = 0; q < 8; ++q) {
            int idx = t + (q << 8);              // 0..2047
            int r = idx >> 6;
            float4 z = {0.f, 0.f, 0.f, 0.f};
            stg[q] = (tl * TROWS + r < n) ? F4[idx] : z;
        }
    };
    if (blockIdx.x < (unsigned)n_tiles) load_tile(blockIdx.x);
    __syncthreads();   // Wt_h2 ready

    for (int tile = blockIdx.x; tile < n_tiles; tile += gridDim.x) {
        // ---- write staged regs to LDS as fp16 ----
        #pragma unroll
        for (int q = 0; q < 8; ++q) {
            int idx = t + (q << 8);
            int r = idx >> 6, c4 = idx & 63;
            rows_h2[r][c4 * 2]     = pk16(stg[q].x, stg[q].y);
            rows_h2[r][c4 * 2 + 1] = pk16(stg[q].z, stg[q].w);
        }
        __syncthreads();

        // ---- prefetch next tile while computing this one ----
        {
            int nt2 = tile + gridDim.x;
            if (nt2 < n_tiles) load_tile(nt2);
        }

        // ---- logits: thread (rl,kl): rows {rl, rl+16} . W[:,kl] via dot2 ----
        float a0 = 0.f, a1 = 0.f;
        #pragma unroll 8
        for (int dd = 0; dd < 32; ++dd) {          // 8 dims per iter
            uint4 wv = *(const uint4*)&Wt_h2[kl][dd << 2];
            uint4 r0 = *(const uint4*)&rows_h2[rl][dd << 2];
            uint4 r1 = *(const uint4*)&rows_h2[rl + 16][dd << 2];
            #pragma unroll
            for (int j = 0; j < 4; ++j) {
                h2 wj = bch2((&wv.x)[j]);
                a0 = fdot2(wj, bch2((&r0.x)[j]), a0);
                a1 = fdot2(wj, bch2((&r1.x)[j]), a1);
            }
        }
        a0 += bk; a1 += bk;

        // ---- softmax over the 16 kl lanes, two rows ----
        float mx0 = a0, mx1 = a1;
        #pragma unroll
        for (int o = 8; o; o >>= 1) {
            mx0 = fmaxf(mx0, __shfl_xor(mx0, o, 16));
            mx1 = fmaxf(mx1, __shfl_xor(mx1, o, 16));
        }
        float e0 = __expf(a0 - mx0), e1 = __expf(a1 - mx1);
        float s0 = e0, s1 = e1;
        #pragma unroll
        for (int o = 8; o; o >>= 1) {
            s0 += __shfl_xor(s0, o, 16);
            s1 += __shfl_xor(s1, o, 16);
        }
        float sv0 = e0 / s0, sv1 = e1 / s1;

        const bool v0 = (tile * TROWS + rl) < n;
        const bool v1 = (tile * TROWS + rl + 16) < n;
        if (v0) { S_out[(((size_t)(tile * TROWS + rl)) << 4) + kl] = sv0; cs_acc += sv0; }
        if (v1) { S_out[(((size_t)(tile * TROWS + rl + 16)) << 4) + kl] = sv1; cs_acc += sv1; }
        S_lds[rl][kl]      = v0 ? sv0 : 0.f;
        S_lds[rl + 16][kl] = v1 ? sv1 : 0.f;
        __syncthreads();

        // fp8 pack: threads t<128: row r=t>>2, 4-elem chunk c=t&3
        if (t < 128) {
            int r = t >> 2, c = t & 3;
            int row = tile * TROWS + r;
            if (row < n) {
                unsigned u = f32_to_e4m3(S_lds[r][4*c])
                           | (f32_to_e4m3(S_lds[r][4*c+1]) << 8)
                           | (f32_to_e4m3(S_lds[r][4*c+2]) << 16)
                           | (f32_to_e4m3(S_lds[r][4*c+3]) << 24);
                S_f8[((size_t)row << 2) + c] = u;
            }
        }

        // ---- P accumulation: thread (kp,cp) owns P[kp][16cp..16cp+15] ----
        #pragma unroll 4
        for (int r = 0; r < TROWS; ++r) {
            float sv = S_lds[r][kp];
            h2 svh = pk16(sv, sv);
            uint4 fa = *(const uint4*)&rows_h2[r][cp << 3];
            uint4 fb = *(const uint4*)&rows_h2[r][(cp << 3) + 4];
            #pragma unroll
            for (int j = 0; j < 4; ++j) {
                Pa[j]     = svh * bch2((&fa.x)[j]) + Pa[j];      // v_pk_fma_f16
                Pa[4 + j] = svh * bch2((&fb.x)[j]) + Pa[4 + j];
            }
        }
        __syncthreads();   // rows_h2 consumed; safe to overwrite next iter
    }

    // ---- flush partials (f32) to private per-block slot ----
    {
        float o16[16];
        #pragma unroll
        for (int j = 0; j < 8; ++j) {
            o16[2*j]     = (float)Pa[j][0];
            o16[2*j + 1] = (float)Pa[j][1];
        }
        float* dst = ws_P + (size_t)blockIdx.x * 4112 + kp * 256 + (cp << 4);
        #pragma unroll
        for (int j = 0; j < 4; ++j)
            *(float4*)&dst[4*j] = make_float4(o16[4*j], o16[4*j+1], o16[4*j+2], o16[4*j+3]);
    }
    cs_red[t] = cs_acc;
    __syncthreads();
    if (t < 16) {
        float ssum = 0.f;
        #pragma unroll
        for (int i = 0; i < 16; ++i) ssum += cs_red[t + (i << 4)];
        ws_P[(size_t)blockIdx.x * 4112 + 4096 + t] = ssum;
    }
}

__global__ void __launch_bounds__(256)
k_reduce(const float* __restrict__ ws_P, float* __restrict__ ws_red, int nb)
{
    const int seg  = blockIdx.x & (NSEG - 1);
    const int jblk = blockIdx.x / NSEG;
    const int idx  = jblk * 256 + threadIdx.x;
    if (idx >= 4112) return;
    const int chunk = (nb + NSEG - 1) / NSEG;
    const int b0 = seg * chunk;
    const int b1 = min(nb, b0 + chunk);
    float s = 0.f;
    for (int bb = b0; bb < b1; ++bb)
        s += ws_P[(size_t)bb * 4112 + idx];
    atomicAdd(&ws_red[idx], s);
}

// fused edge kernel, all 3 graphs; 4 edges/iter, high occupancy.
__global__ void __launch_bounds__(256, 4)
k_edge(const int* __restrict__ src0, const int* __restrict__ dst0,
       const float* __restrict__ val0, int n0,
       const int* __restrict__ src1, const int* __restrict__ dst1,
       const float* __restrict__ val1, int n1,
       const int* __restrict__ src2, const int* __restrict__ dst2,
       const float* __restrict__ val2, int n2,
       const uint4* __restrict__ S8, float* __restrict__ ws_e,
       int b0, int b1)
{
#ifndef HW_FP8
    __shared__ float lut[256];
    if (threadIdx.x < 256) {
        int i = threadIdx.x;
        int e_ = (i >> 3) & 15, m_ = i & 7, s_ = i >> 7;
        float v = e_ ? ldexpf((float)(8 + m_), e_ - 10) : ldexpf((float)m_, -9);
        lut[i] = s_ ? -v : v;
    }
    __syncthreads();
    const float* lutp = lut;
#else
    const float* lutp = nullptr;
#endif

    int g, bb, nblk, nE;
    const int* src; const int* dst; const float* val;
    if ((int)blockIdx.x < b0)      { g = 0; bb = blockIdx.x;      nblk = b0;             src = src0; dst = dst0; val = val0; nE = n0; }
    else if ((int)blockIdx.x < b1) { g = 1; bb = blockIdx.x - b0; nblk = b1 - b0;        src = src1; dst = dst1; val = val1; nE = n1; }
    else                           { g = 2; bb = blockIdx.x - b1; nblk = gridDim.x - b1; src = src2; dst = dst2; val = val2; nE = n2; }

    float m_acc = 0.f, tr_acc = 0.f;
    float gds[16];
    #pragma unroll
    for (int k = 0; k < 16; ++k) gds[k] = 0.f;

    const int nv = nE >> 2;                    // 4 edges per thread-iter
    const iv4* s4 = (const iv4*)src;
    const iv4* d4 = (const iv4*)dst;
    const fv4* v4 = (const fv4*)val;
    const int stride = nblk * 256;

    for (int i = bb * 256 + threadIdx.x; i < nv; i += stride) {
        iv4 sa = __builtin_nontemporal_load(&s4[i]);
        iv4 da = __builtin_nontemporal_load(&d4[i]);
        fv4 va = __builtin_nontemporal_load(&v4[i]);
        uint4 rs[4], rd[4];
        #pragma unroll
        for (int e = 0; e < 4; ++e) {
            rs[e] = S8[sa[e]];
            rd[e] = S8[da[e]];
        }
        #pragma unroll
        for (int e = 0; e < 4; ++e) {
            float sv[16], dv[16];
            decode16(rs[e], sv, lutp);
            decode16(rd[e], dv, lutp);
            float v = va[e];
            float dot = 0.f;
            #pragma unroll
            for (int k = 0; k < 16; ++k) dot = fmaf(sv[k], dv[k], dot);
            m_acc += v;
            tr_acc = fmaf(v, dot, tr_acc);
            #pragma unroll
            for (int k = 0; k < 16; ++k) gds[k] = fmaf(v, dv[k], gds[k]);
        }
    }

    // tail (nE % 4): handled by block 0 of this graph
    if (bb == 0) {
        int e = (nv << 2) + threadIdx.x;
        if (e < nE) {
            float sv[16], dv[16];
            decode16(S8[src[e]], sv, lutp);
            decode16(S8[dst[e]], dv, lutp);
            float v = val[e];
            float dot = 0.f;
            #pragma unroll
            for (int k = 0; k < 16; ++k) dot = fmaf(sv[k], dv[k], dot);
            m_acc += v;
            tr_acc = fmaf(v, dot, tr_acc);
            #pragma unroll
            for (int k = 0; k < 16; ++k) gds[k] = fmaf(v, dv[k], gds[k]);
        }
    }

    #pragma unroll
    for (int o = 32; o; o >>= 1) {
        m_acc  += __shfl_xor(m_acc, o);
        tr_acc += __shfl_xor(tr_acc, o);
        #pragma unroll
        for (int k = 0; k < 16; ++k) gds[k] += __shfl_xor(gds[k], o);
    }
    __shared__ float wred[4][18];
    const int wid = threadIdx.x >> 6, lane = threadIdx.x & 63;
    if (lane == 0) {
        wred[wid][0] = m_acc; wred[wid][1] = tr_acc;
        #pragma unroll
        for (int k = 0; k < 16; ++k) wred[wid][2 + k] = gds[k];
    }
    __syncthreads();
    if (threadIdx.x < 18) {
        float s = wred[0][threadIdx.x] + wred[1][threadIdx.x]
                + wred[2][threadIdx.x] + wred[3][threadIdx.x];
        ws_e[(size_t)g * 18 * EGRID + (size_t)threadIdx.x * EGRID + bb] = s;
    }
}

// one block per (g,slot): coalesced reduce of per-graph partials -> G54
__global__ void __launch_bounds__(256)
k_ereduce(const float* __restrict__ ws_e, float* __restrict__ G54,
          int g0, int g1, int g2)
{
    const int p = blockIdx.x;            // 0..53
    const int g = p / 18, slot = p % 18;
    int grids[3] = {g0, g1, g2};
    const int gb = grids[g];
    const float* base = ws_e + (size_t)g * 18 * EGRID + (size_t)slot * EGRID;

    const int t = threadIdx.x;
    float s = 0.f;
    for (int bb = t; bb < gb; bb += 256) s += base[bb];
    #pragma unroll
    for (int o = 32; o; o >>= 1) s += __shfl_xor(s, o);

    __shared__ float wr[4];
    if ((t & 63) == 0) wr[t >> 6] = s;
    __syncthreads();
    if (t == 0) G54[p] = wr[0] + wr[1] + wr[2] + wr[3];
}

__global__ void __launch_bounds__(256)
k_final(const float* __restrict__ ws_red, const float* __restrict__ G54,
        const void* __restrict__ lamda_ptr, float* __restrict__ out, int n)
{
    __shared__ float G[54];
    const int t = threadIdx.x;
    if (t < 54) G[t] = G54[t];
    __syncthreads();

    const float* P  = ws_red;
    const float* cs = ws_red + 4096;

    const float scale = 1.0507009873554805f;
    const float alpha = 1.6732632423543772f;
    for (int idx = t; idx < 4096; idx += 256) {
        int k = idx >> 8;
        float x = P[idx] / cs[k];
        float y = x > 0.f ? scale * x : scale * alpha * (expf(x) - 1.f);
        out[idx] = y;
    }

    if (t == 0) {
        int   li = *(const int*)lamda_ptr;
        float lf = *(const float*)lamda_ptr;
        float lamda = (li > -100000 && li < 100000) ? (float)li : lf;

        float m = G[0], trA = G[1];
        float ds2 = 0.f;
        for (int k = 0; k < 16; ++k) ds2 += G[2 + k] * G[2 + k];
        float spectral = -(trA - ds2 / (2.f * m)) / (2.f * m);

        float Q[2], gm[2];
        for (int g = 0; g < 2; ++g) {
            const float* Gg = G + 18 * (g + 1);
            float mg = Gg[0], trg = Gg[1];
            float gds2 = 0.f;
            for (int k = 0; k < 16; ++k) gds2 += Gg[2 + k] * Gg[2 + k];
            float safe = mg > 0.f ? mg : 1.f;
            float q = (trg - gds2 / (2.f * safe)) / (2.f * m);
            Q[g]  = mg > 0.f ? q : 0.f;
            gm[g] = mg;
        }
        float Qmin = fminf(Q[0], Q[1]);
        float gmean = 0.5f * (gm[0] + gm[1]);
        float fairness = (m / (gmean + 1e-8f)) * (-Qmin);

        float csn = 0.f;
        for (int k = 0; k < 16; ++k) csn += cs[k] * cs[k];
        float collapse = (sqrtf(csn) / (float)n) * 4.f - 1.f;

        out[4096 + (size_t)n * 16] = spectral + lamda * fairness + 0.1f * collapse;
    }
}

extern "C" void kernel_launch(void* const* d_in, const int* in_sizes, int n_in,
                              void* d_out, int out_size, void* d_ws, size_t ws_size,
                              hipStream_t stream)
{
    const float* F       = (const float*)d_in[0];
    const float* W       = (const float*)d_in[1];
    const float* b       = (const float*)d_in[2];
    const int*   adj_src = (const int*)d_in[3];
    const int*   adj_dst = (const int*)d_in[4];
    const float* adj_val = (const float*)d_in[5];
    const int*   g1_src  = (const int*)d_in[6];
    const int*   g1_dst  = (const int*)d_in[7];
    const float* g1_val  = (const float*)d_in[8];
    const int*   g2_src  = (const int*)d_in[9];
    const int*   g2_dst  = (const int*)d_in[10];
    const float* g2_val  = (const float*)d_in[11];
    const void*  lamda_p = d_in[12];

    const int n  = in_sizes[0] / 256;
    const int nE = in_sizes[3];
    const int n1 = in_sizes[6];
    const int n2 = in_sizes[9];

    float* out   = (float*)d_out;
    float* S_out = out + 4096;

    float* ws   = (float*)d_ws;
    float* ws_e = ws + OFF_E;
    float* ws_r = ws + OFF_R;
    float* ws_g = ws + OFF_G;
    unsigned* S8 = (unsigned*)(ws + OFF_F8);
    const size_t off_p = (size_t)OFF_F8 + (size_t)n * 4;
    float* ws_P = ws + off_p;

    const int n_tiles = (n + TROWS - 1) / TROWS;
    long avail = ((long)(ws_size / 4) - (long)off_p) / 4112;
    int grid1 = n_tiles < G1_MAX ? n_tiles : G1_MAX;
    if (avail < grid1) grid1 = (int)avail;
    if (grid1 < 1) grid1 = 1;

    (void)hipMemsetAsync(ws_r, 0, 4112 * sizeof(float), stream);

    k_rows<<<grid1, 256, 0, stream>>>(F, W, b, S_out, S8, ws_P, n, n_tiles);
    k_reduce<<<17 * NSEG, 256, 0, stream>>>(ws_P, ws_r, grid1);

    const int b0 = BLK0, b1g = BLK12, b2g = BLK12;
    k_edge<<<b0 + b1g + b2g, 256, 0, stream>>>(
        adj_src, adj_dst, adj_val, nE,
        g1_src, g1_dst, g1_val, n1,
        g2_src, g2_dst, g2_val, n2,
        (const uint4*)S8, ws_e, b0, b0 + b1g);

    k_ereduce<<<54, 256, 0, stream>>>(ws_e, ws_g, b0, b1g, b2g);
    k_final<<<1, 256, 0, stream>>>(ws_r, ws_g, lamda_p, out, n);
}